// Round 1
// 360.108 us; speedup vs baseline: 1.0472x; 1.0472x over previous
//
#include <hip/hip_runtime.h>
#include <cstdint>
#include <cstddef>

// ---------------- common ----------------
typedef __attribute__((ext_vector_type(8))) short short8;   // 8 x bf16 (4 VGPR)
typedef __attribute__((ext_vector_type(4))) short short4_;  // 4 x bf16 (2 VGPR)
typedef __attribute__((ext_vector_type(4))) float f32x4;    // MFMA C/D
typedef __attribute__((ext_vector_type(2))) unsigned int uint2_;

__device__ inline unsigned short bf16rne(float f) {
    uint32_t u = __builtin_bit_cast(uint32_t, f);
    u += 0x7fffu + ((u >> 16) & 1u);
    return (unsigned short)(u >> 16);
}

// async global->LDS, 16 B per lane. LDS dest = wave-uniform base + lane*16.
// CONTRACT (m104/m108): data lands at base + laneid*16 regardless of per-lane
// pointer; layout must be hole-free in lane order, ALL 64 lanes active.
#define GLDS(g, l)                                                              \
    __builtin_amdgcn_global_load_lds(                                           \
        (const __attribute__((address_space(1))) void*)(g),                     \
        (__attribute__((address_space(3))) void*)(l), 16, 0, 0)

// ---------------- fp32 -> bf16 convert ----------------
__global__ void cvt_kernel(const float* __restrict__ src,
                           unsigned short* __restrict__ dst, int n8) {
    int i = blockIdx.x * blockDim.x + threadIdx.x;
    if (i >= n8) return;
    const float4* s = (const float4*)src + (size_t)i * 2;
    float4 a = s[0], b = s[1];
    uint32_t w0 = bf16rne(a.x) | ((uint32_t)bf16rne(a.y) << 16);
    uint32_t w1 = bf16rne(a.z) | ((uint32_t)bf16rne(a.w) << 16);
    uint32_t w2 = bf16rne(b.x) | ((uint32_t)bf16rne(b.y) << 16);
    uint32_t w3 = bf16rne(b.z) | ((uint32_t)bf16rne(b.w) << 16);
    uint4 o; o.x = w0; o.y = w1; o.z = w2; o.w = w3;
    ((uint4*)dst)[i] = o;
}

// ---------------- QKV projection GEMM ----------------
// C[i][n] = sum_k X[i][k] * W[n][k] + b[n];  M = 128*gridDim.y, K=768, N=2304
// q,k stored bf16 as (b*12+h, 1024, 64) row-major.
// v stored TRANSPOSED: (b*12+h, 64, 1024)  [d-major, for attn PV A-frags]
__global__ __launch_bounds__(256) void qkv_gemm(
    const unsigned short* __restrict__ X, const unsigned short* __restrict__ W,
    const float* __restrict__ bqkv,
    unsigned short* __restrict__ qo, unsigned short* __restrict__ ko,
    unsigned short* __restrict__ vo)
{
    __shared__ unsigned short smem[16896];   // As[8192] Bs[8192] | epilogue Cs 128x132
    unsigned short* As = smem;
    unsigned short* Bs = smem + 8192;

    const int tid  = threadIdx.x;
    const int m0   = blockIdx.y * 128;
    const int n0   = blockIdx.x * 128;
    const int wid  = tid >> 6;
    const int lane = tid & 63;
    const int m16  = lane & 15;
    const int quad = lane >> 4;
    const int wm   = wid >> 1, wn = wid & 1;

    f32x4 acc[4][4];
    #pragma unroll
    for (int i = 0; i < 4; i++)
        #pragma unroll
        for (int j = 0; j < 4; j++) acc[i][j] = (f32x4){0.f, 0.f, 0.f, 0.f};

    for (int kt = 0; kt < 12; ++kt) {
        const int k0 = kt * 64;
        #pragma unroll
        for (int rd = 0; rd < 4; ++rd) {
            int id = rd * 256 + tid;
            int row = id >> 3, c = id & 7;
            GLDS(X + (size_t)(m0 + row) * 768 + k0 + c * 8, &As[id * 8]);
        }
        #pragma unroll
        for (int rd = 0; rd < 4; ++rd) {
            int id = rd * 256 + tid;
            int row = id >> 3, c = id & 7;
            GLDS(W + (size_t)(n0 + row) * 768 + k0 + c * 8, &Bs[id * 8]);
        }
        __syncthreads();
        #pragma unroll
        for (int ks = 0; ks < 2; ++ks) {
            short8 a[4], b[4];
            #pragma unroll
            for (int mb = 0; mb < 4; mb++)
                a[mb] = *(const short8*)&As[(wm * 64 + mb * 16 + m16) * 64 + ks * 32 + quad * 8];
            #pragma unroll
            for (int nb = 0; nb < 4; nb++)
                b[nb] = *(const short8*)&Bs[(wn * 64 + nb * 16 + m16) * 64 + ks * 32 + quad * 8];
            #pragma unroll
            for (int mb = 0; mb < 4; mb++)
                #pragma unroll
                for (int nb = 0; nb < 4; nb++)
                    acc[mb][nb] = __builtin_amdgcn_mfma_f32_16x16x32_bf16(
                        a[mb], b[nb], acc[mb][nb], 0, 0, 0);
        }
        __syncthreads();
    }

    float bias_n[4];
    #pragma unroll
    for (int nb = 0; nb < 4; nb++) bias_n[nb] = bqkv[n0 + wn * 64 + nb * 16 + m16];

    const int which = n0 / 768;
    const int hbase = (n0 % 768) / 64;
    const int bI  = m0 >> 10;      // batch index
    const int ns0 = m0 & 1023;

    if (which == 2) {
        // V: write transposed directly from acc (C-layout lane holds 4 consecutive
        // pos = quad*4+r for a fixed d-column) -> b64 stores into (bh,64,1024).
        #pragma unroll
        for (int mb = 0; mb < 4; ++mb)
            #pragma unroll
            for (int nb = 0; nb < 4; ++nb) {
                int n  = wn * 64 + nb * 16 + m16;
                int hh = hbase + (n >> 6);
                int d  = n & 63;
                int pos = ns0 + wm * 64 + mb * 16 + quad * 4;
                short4_ v4;
                #pragma unroll
                for (int r = 0; r < 4; ++r)
                    v4[r] = (short)bf16rne(acc[mb][nb][r] + bias_n[nb]);
                *(short4_*)(vo + ((size_t)(bI * 12 + hh) * 64 + d) * 1024 + pos) = v4;
            }
        return;
    }

    // Q/K: bias, bf16, repack via LDS (stride 132), row-major (bh,1024,64) stores
    #pragma unroll
    for (int mb = 0; mb < 4; mb++)
        #pragma unroll
        for (int nb = 0; nb < 4; nb++)
            #pragma unroll
            for (int r = 0; r < 4; r++) {
                float v = acc[mb][nb][r] + bias_n[nb];
                smem[(wm * 64 + mb * 16 + quad * 4 + r) * 132 + wn * 64 + nb * 16 + m16] =
                    bf16rne(v);
            }
    __syncthreads();

    unsigned short* outp = (which == 0) ? qo : ko;
    #pragma unroll
    for (int rd = 0; rd < 8; ++rd) {
        int id = rd * 256 + tid;
        int row = id >> 4, c = id & 15;
        short4_ lo = *(const short4_*)&smem[row * 132 + c * 8];
        short4_ hi = *(const short4_*)&smem[row * 132 + c * 8 + 4];
        short8 v8 = __builtin_shufflevector(lo, hi, 0, 1, 2, 3, 4, 5, 6, 7);
        int h  = hbase + (c >> 3);
        int dc = (c & 7) * 8;
        unsigned short* dst =
            outp + ((size_t)(bI * 12 + h) * 1024 + ns0 + row) * 64 + dc;
        *(short8*)dst = v8;
    }
}

// ---------------- flash attention (S^T formulation, double-buffered) ----------
// 1-D grid nbh*16, XCD-swizzled: f=(xcd | 8*(q | 16*bhl)), bh=xcd*nbh8+bhl.
// All 16 q-tiles of one bh land on one XCD so K/V stay L2-resident per XCD.
// 4 waves; wave w owns q rows q0+w*16..+16.
// S^T = K·Q^T via 16x16x32 (C col = q-row, rows = pos) -> softmax is per-lane
// scalar state + 2 shuffles; P^T packed in registers via v_perm_b32 truncation
// (B-frag of 16x16x16bf16_1k) for O^T += V^T·P^T (no P LDS round-trip).
//
// R6 change (theory: latency-bound, 16.7% MfmaUtil / 30% VALUBusy / 6% HBM):
//   KVBLK 128 -> 64 and DOUBLE-BUFFER within the same 32 KB LDS footprint
//   (2 x (Ks 8K + Vs 8K)) -> still 5 blocks/CU. T3 2-phase schedule: the
//   GLDS for tile t+1 issue BEFORE the compute on tile t; the single
//   vmcnt(0)+barrier per iter then drains loads that have had a full
//   compute phase (~500 cyc) to land, instead of serializing issue->drain.
//   Bias float4 loads software-pipelined one iter ahead (drained for free
//   by the end-of-iter barrier -> zero-wait use in softmax).
//   T13 defer-rescale THR=0: numerically identical to baseline, skips the
//   16-wide acc rescale + exp on tiles where no row max grew.
//   Ks slot = pos*8 + (db ^ (pos&7)) -> b128 reads hit 8 dwords/bank (min)
//   Vs slot = pb*64 + d              -> b64  reads hit 4 dwords/bank (min)
__global__ __launch_bounds__(256, 5) void attn_kernel(
    const unsigned short* __restrict__ Q, const unsigned short* __restrict__ K,
    const unsigned short* __restrict__ Vt, const float* __restrict__ bias,
    const float* __restrict__ dvec, float* __restrict__ out, int nbh8)
{
    __shared__ unsigned short Ks[2][4096];   // 2 x 512 slots * 8 elems = 16 KB
    __shared__ unsigned short Vs[2][4096];   // 2 x 512 slots * 8 elems = 16 KB

    const int tid  = threadIdx.x;
    const int wid  = tid >> 6;
    const int lane = tid & 63;
    const int m16  = lane & 15;
    const int quad = lane >> 4;

    const int f    = blockIdx.x;
    const int xcd  = f & 7;
    const int r_   = f >> 3;
    const int qt   = r_ & 15;
    const int bhl  = r_ >> 4;
    const int bh   = xcd * nbh8 + bhl;
    const int b = bh / 12, h = bh % 12;
    const int q0 = qt * 64;
    const int qrow = q0 + wid * 16 + m16;   // this lane's q row (column of S^T)

    const unsigned short* Qb = Q  + (size_t)bh * 65536;
    const unsigned short* Kb = K  + (size_t)bh * 65536;
    const unsigned short* Vb = Vt + (size_t)bh * 65536;
    const float* brow = bias + (size_t)qrow * 1024 + quad * 4;

    // kv-invariant staging source offsets (hole-free, all lanes active)
    int k_src[2], v_src[2];
    #pragma unroll
    for (int rd = 0; rd < 2; ++rd) {
        int id = rd * 256 + tid;                  // 0..511
        int pos = id >> 3, dbs = id & 7;
        int db = dbs ^ (pos & 7);                 // un-swizzle: slot id holds this db
        k_src[rd] = pos * 64 + db * 8;
        int pb = id >> 6, d = id & 63;            // pb 0..7
        v_src[rd] = d * 1024 + pb * 8;
    }

    // Q fragments: B-operand of 16x16x32 (lane n=m16 holds dims quad*8..+8)
    short8 qf0 = *(const short8*)(Qb + (size_t)qrow * 64 + quad * 8);
    short8 qf1 = *(const short8*)(Qb + (size_t)qrow * 64 + 32 + quad * 8);

    f32x4 acc[4];
    #pragma unroll
    for (int nb = 0; nb < 4; nb++) acc[nb] = (f32x4){0.f, 0.f, 0.f, 0.f};
    float m_i = -3.0e38f, l_i = 0.f;

    // prologue: stage tile 0 + preload bias tile 0
    #pragma unroll
    for (int rd = 0; rd < 2; ++rd)
        GLDS(Kb + k_src[rd], &Ks[0][(rd * 256 + tid) * 8]);
    #pragma unroll
    for (int rd = 0; rd < 2; ++rd)
        GLDS(Vb + v_src[rd], &Vs[0][(rd * 256 + tid) * 8]);
    float4 bv[4];
    #pragma unroll
    for (int cb = 0; cb < 4; ++cb) bv[cb] = *(const float4*)(brow + cb * 16);
    __syncthreads();

    for (int kv = 0; kv < 16; ++kv) {
        const int cur = kv & 1;
        const int k0n = (kv + 1) * 64;

        // prefetch tile kv+1 (lands during this iter's compute; barrier drains)
        float4 bvn[4];
        if (kv < 15) {
            #pragma unroll
            for (int rd = 0; rd < 2; ++rd)
                GLDS(Kb + (size_t)k0n * 64 + k_src[rd],
                     &Ks[cur ^ 1][(rd * 256 + tid) * 8]);
            #pragma unroll
            for (int rd = 0; rd < 2; ++rd)
                GLDS(Vb + (size_t)k0n + v_src[rd],
                     &Vs[cur ^ 1][(rd * 256 + tid) * 8]);
            #pragma unroll
            for (int cb = 0; cb < 4; ++cb)
                bvn[cb] = *(const float4*)(brow + k0n + cb * 16);
        }

        // S^T = K·Q^T : sc[cb] rows = pos cb*16+quad*4+r, col = qrow(m16)
        f32x4 sc[4];
        #pragma unroll
        for (int cb = 0; cb < 4; ++cb) sc[cb] = (f32x4){0.f, 0.f, 0.f, 0.f};
        #pragma unroll
        for (int ks = 0; ks < 2; ++ks) {
            #pragma unroll
            for (int cb = 0; cb < 4; ++cb) {
                int pos = cb * 16 + m16;
                int slot = pos * 8 + ((ks * 4 + quad) ^ (m16 & 7));
                short8 a = *(const short8*)&Ks[cur][slot * 8];
                sc[cb] = __builtin_amdgcn_mfma_f32_16x16x32_bf16(
                    a, (ks == 0) ? qf0 : qf1, sc[cb], 0, 0, 0);
            }
        }

        // scale + bias (pipelined registers, zero-wait) + running max
        float mx = -3.0e38f;
        #pragma unroll
        for (int cb = 0; cb < 4; ++cb) {
            sc[cb][0] = sc[cb][0] * 0.125f + bv[cb].x;
            sc[cb][1] = sc[cb][1] * 0.125f + bv[cb].y;
            sc[cb][2] = sc[cb][2] * 0.125f + bv[cb].z;
            sc[cb][3] = sc[cb][3] * 0.125f + bv[cb].w;
            mx = fmaxf(mx, fmaxf(fmaxf(sc[cb][0], sc[cb][1]), fmaxf(sc[cb][2], sc[cb][3])));
        }
        mx = fmaxf(mx, __shfl_xor(mx, 16, 64));
        mx = fmaxf(mx, __shfl_xor(mx, 32, 64));

        // T13 defer-rescale (THR=0: exact — skipped only when per-row max
        // didn't grow, in which case the rescale would be exp(0)=1 anyway)
        if (!__all(mx <= m_i)) {
            float mnew = fmaxf(m_i, mx);
            float al = __expf(m_i - mnew);
            m_i = mnew;
            l_i *= al;
            #pragma unroll
            for (int nb = 0; nb < 4; nb++) {
                acc[nb][0] *= al; acc[nb][1] *= al;
                acc[nb][2] *= al; acc[nb][3] *= al;
            }
        }

        // exp + row-sum + pack P^T via v_perm_b32 truncation (2 elems/instr)
        float rs = 0.f;
        short4_ pf[4];
        #pragma unroll
        for (int cb = 0; cb < 4; ++cb) {
            float p0 = __expf(sc[cb][0] - m_i);
            float p1 = __expf(sc[cb][1] - m_i);
            float p2 = __expf(sc[cb][2] - m_i);
            float p3 = __expf(sc[cb][3] - m_i);
            rs += (p0 + p1) + (p2 + p3);
            uint2_ pd;
            pd[0] = __builtin_amdgcn_perm(__builtin_bit_cast(uint32_t, p1),
                                          __builtin_bit_cast(uint32_t, p0), 0x07060302u);
            pd[1] = __builtin_amdgcn_perm(__builtin_bit_cast(uint32_t, p3),
                                          __builtin_bit_cast(uint32_t, p2), 0x07060302u);
            pf[cb] = __builtin_bit_cast(short4_, pd);
        }
        rs += __shfl_xor(rs, 16, 64);
        rs += __shfl_xor(rs, 32, 64);
        l_i += rs;

        // O^T += V^T · P^T  (A = V^T frag from LDS, B = P^T in registers)
        #pragma unroll
        for (int ks = 0; ks < 4; ++ks) {
            #pragma unroll
            for (int nb = 0; nb < 4; ++nb) {
                int slot = (ks * 2 + (quad >> 1)) * 64 + nb * 16 + m16;
                short4_ av = *(const short4_*)&Vs[cur][slot * 8 + (quad & 1) * 4];
                acc[nb] = __builtin_amdgcn_mfma_f32_16x16x16bf16_1k(av, pf[ks], acc[nb], 0, 0, 0);
            }
        }

        // one barrier per iter: waits this iter's LDS reads AND drains the
        // prefetch (issued a full compute phase ago -> cheap)
        __syncthreads();
        if (kv < 15) {
            #pragma unroll
            for (int cb = 0; cb < 4; ++cb) bv[cb] = bvn[cb];
        }
    }

    // epilogue: out = d[qrow]/l * O ; O^T C-layout: lane holds d = nb*16+quad*4+r
    float scl = dvec[qrow] / l_i;
    #pragma unroll
    for (int nb = 0; nb < 4; ++nb) {
        float4 o;
        o.x = acc[nb][0] * scl; o.y = acc[nb][1] * scl;
        o.z = acc[nb][2] * scl; o.w = acc[nb][3] * scl;
        *(float4*)(out + ((size_t)b * 1024 + qrow) * 768 + h * 64 + nb * 16 + quad * 4) = o;
    }
}

// ---------------- launch ----------------
// xb (bf16 x, 25165824 B) lives in the upper half of d_out; every gemm that
// reads an xb region precedes (stream order) any attn write to that region.
// Workspace is layout-adaptive on ws_size (constant across calls => the same
// work every call):
//   full path  (ws >= 79,036,416 B): wb + full-size q/k/vT  -> 1 gemm + 1 attn
//   chunk path (ws >= 22,413,312 B): wb + 4-batch q/k/vT    -> 4x(gemm+attn)
extern "C" void kernel_launch(void* const* d_in, const int* in_sizes, int n_in,
                              void* d_out, int out_size, void* d_ws, size_t ws_size,
                              hipStream_t stream) {
    const float* x     = (const float*)d_in[0];   // (16,1024,768)
    const float* w     = (const float*)d_in[1];   // (2304,768)
    const float* bqkv  = (const float*)d_in[2];   // (2304,)
    const float* dvec  = (const float*)d_in[3];   // (1024,)
    const float* bbias = (const float*)d_in[4];   // (1024,1024)
    float* out = (float*)d_out;

    char* ws = (char*)d_ws;
    unsigned short* wb = (unsigned short*)ws;                        // 2304*768 bf16
    unsigned short* xb = (unsigned short*)((char*)d_out + 25165824); // 16*1024*768 bf16

    cvt_kernel<<<6144, 256, 0, stream>>>(x, xb, 1572864);            // all x -> bf16
    cvt_kernel<<<864, 256, 0, stream>>>(w, wb, 221184);              // w -> bf16

    const size_t NEED_FULL = 3538944ull + 3ull * 25165824ull;        // 79,036,416
    if (ws_size >= NEED_FULL) {
        unsigned short* qb = (unsigned short*)(ws + 3538944);        // 16*12*1024*64
        unsigned short* kb = qb + 12582912;
        unsigned short* vb = kb + 12582912;                          // V^T (bh,64,1024)
        qkv_gemm<<<dim3(18, 128), 256, 0, stream>>>(xb, wb, bqkv, qb, kb, vb);
        attn_kernel<<<3072, 256, 0, stream>>>(qb, kb, vb, bbias, dvec, out, 24);
    } else {
        unsigned short* qb = (unsigned short*)(ws + 3538944);        // 4*12*1024*64
        unsigned short* kb = qb + 3145728;
        unsigned short* vb = kb + 3145728;                           // V^T (bh,64,1024)
        for (int c = 0; c < 4; ++c) {
            const unsigned short* xc = xb + (size_t)c * 3145728;     // 4 batches
            qkv_gemm<<<dim3(18, 32), 256, 0, stream>>>(xc, wb, bqkv, qb, kb, vb);
            attn_kernel<<<768, 256, 0, stream>>>(
                qb, kb, vb, bbias, dvec, out + (size_t)c * 3145728, 6);
        }
    }
}